// Round 12
// baseline (291.418 us; speedup 1.0000x reference)
//
#include <hip/hip_runtime.h>
#include <hip/hip_bf16.h>
#include <cstdint>

#define HID 128
#define GM 128          // rows per GEMM block
#define NBIN 512        // low-9-bit buckets
#define CHUNK 2048      // edges per histogram/route block
#define MAXHI 1024      // max (n_nodes/NBIN) supported

typedef __attribute__((ext_vector_type(8))) short bf16x8;
typedef __attribute__((ext_vector_type(4))) float f32x4;

__device__ __forceinline__ unsigned short f2bf(float f) {
    union { __hip_bfloat16 h; unsigned short u; } c;
    c.h = __float2bfloat16(f);
    return c.u;
}
__device__ __forceinline__ float bf2f(unsigned short u) {
    union { unsigned int i; float f; } c;
    c.i = ((unsigned int)u) << 16;
    return c.f;
}
__device__ __forceinline__ unsigned int pack2(unsigned short a, unsigned short b) {
    return (unsigned int)a | ((unsigned int)b << 16);
}
__device__ __forceinline__ bf16x8 ld_frag(const unsigned int* p) {
    union { uint4 u; bf16x8 f; } c;
    c.u = *(const uint4*)p;
    return c.f;
}

// exclusive block scan over 256 threads (wave shfl + LDS wave totals).
__device__ __forceinline__ int block_scan_excl(int v, int t, int* wtot, int* tot) {
    int lane = t & 63, wv = t >> 6;
    int incl = v;
#pragma unroll
    for (int off = 1; off < 64; off <<= 1) {
        int u = __shfl_up(incl, off);
        if (lane >= off) incl += u;
    }
    if (lane == 63) wtot[wv] = incl;
    __syncthreads();
    int woff = 0;
    for (int w = 0; w < wv; ++w) woff += wtot[w];
    if (tot) *tot = wtot[0] + wtot[1] + wtot[2] + wtot[3];
    __syncthreads();   // allow wtot reuse
    return woff + incl - v;
}

// ---------------- fused prep: zl/zr tables (blocks < max_z) + W split (rest) ----------------
__global__ void k_prep(const float* __restrict__ z_emb, const float* __restrict__ Wl,
                       const float* __restrict__ Wr, const float* __restrict__ bl,
                       float* __restrict__ zl, float* __restrict__ zr,
                       unsigned short* __restrict__ wh, unsigned short* __restrict__ wlo,
                       int* __restrict__ done, int max_z) {
    int t = threadIdx.x;
    if ((int)blockIdx.x < max_z) {
        if (blockIdx.x == 0 && t == 0) done[0] = 0;   // reset colscan completion counter
        __shared__ float row[HID];
        int r = blockIdx.x;
        if (t < HID) row[t] = z_emb[(size_t)r * HID + t];
        __syncthreads();
        int d = t & 127;
        const float* w = (t < 128 ? Wl : Wr) + (size_t)d * HID;
        float acc = 0.f;
#pragma unroll
        for (int k4 = 0; k4 < HID / 4; ++k4) {
            float4 wv = *(const float4*)(w + k4 * 4);
            float4 hv = *(const float4*)&row[k4 * 4];
            acc += wv.x * hv.x + wv.y * hv.y + wv.z * hv.z + wv.w * hv.w;
        }
        if (t < 128) zl[(size_t)r * HID + d] = acc;
        else         zr[(size_t)r * HID + d] = acc + bl[d];
    } else {
        int idx = (blockIdx.x - max_z) * 256 + t;
        if (idx >= 3 * HID * 2 * HID) return;
        int l = idx / (HID * 2 * HID);
        int r = idx - l * (HID * 2 * HID);
        int d = r >> 8;
        int k = r & 255;
        float v = (k < HID) ? Wl[((size_t)l * HID + d) * HID + k]
                            : Wr[((size_t)l * HID + d) * HID + (k - HID)];
        unsigned short h = f2bf(v);
        unsigned short lo = f2bf(v - bf2f(h));
        wh[idx] = h;
        wlo[idx] = lo;
    }
}

// ---------------- pass 1a: per-block 512-bin histogram of dst low bits ----------------
__global__ __launch_bounds__(256) void k_hist(const int* __restrict__ dst,
                                              int* __restrict__ hist, int n_edges) {
    __shared__ int h[NBIN];
    int t = threadIdx.x;
    h[t] = 0; h[t + 256] = 0;
    __syncthreads();
    int base = blockIdx.x * CHUNK;
#pragma unroll
    for (int j = 0; j < CHUNK / 256; ++j) {
        int e = base + j * 256 + t;
        if (e < n_edges) atomicAdd(&h[dst[e] & (NBIN - 1)], 1);
    }
    __syncthreads();
    hist[(size_t)blockIdx.x * NBIN + t] = h[t];
    hist[(size_t)blockIdx.x * NBIN + t + 256] = h[t + 256];
}

// ---------------- pass 1b+1c: per-bin scan over blocks; last block scans bin totals ----
__global__ __launch_bounds__(256) void k_colscan(int* __restrict__ hist,
                                                 int* __restrict__ bintotal,
                                                 int* __restrict__ binbase,
                                                 int* __restrict__ done, int B) {
    __shared__ int wtot[4];
    __shared__ int slast;
    int k = blockIdx.x, t = threadIdx.x;
    int run = 0;
    for (int base = 0; base < B; base += 256) {
        int b = base + t;
        int v = (b < B) ? hist[(size_t)b * NBIN + k] : 0;
        int tot;
        int excl = block_scan_excl(v, t, wtot, &tot);
        if (b < B) hist[(size_t)b * NBIN + k] = run + excl;
        run += tot;
    }
    if (t == 0) {
        atomicExch(&bintotal[k], run);      // device-coherent publish
        __threadfence();
        slast = (atomicAdd(done, 1) == NBIN - 1) ? 1 : 0;
    }
    __syncthreads();
    if (!slast) return;
    __threadfence();
    int a0 = atomicAdd(&bintotal[2 * t], 0);        // device-coherent read
    int a1 = atomicAdd(&bintotal[2 * t + 1], 0);
    int excl = block_scan_excl(a0 + a1, t, wtot, nullptr);
    binbase[2 * t] = excl;
    binbase[2 * t + 1] = excl + a0;
    if (t == 255) binbase[NBIN] = excl + a0 + a1;
}

// ---------------- pass 1d: route edges into bin regions (LDS ranks, no global atomics) --
__global__ __launch_bounds__(256) void k_route(const int* __restrict__ src,
                                               const int* __restrict__ dst,
                                               const int* __restrict__ histex,
                                               const int* __restrict__ binbase,
                                               int2* __restrict__ ebuf, int n_edges) {
    __shared__ int h2[NBIN];
    __shared__ int basel[NBIN];
    int t = threadIdx.x;
    h2[t] = 0; h2[t + 256] = 0;
    basel[t]       = binbase[t]       + histex[(size_t)blockIdx.x * NBIN + t];
    basel[t + 256] = binbase[t + 256] + histex[(size_t)blockIdx.x * NBIN + t + 256];
    __syncthreads();
    int base = blockIdx.x * CHUNK;
#pragma unroll
    for (int j = 0; j < CHUNK / 256; ++j) {
        int e = base + j * 256 + t;
        if (e < n_edges) {
            int d = dst[e], s = src[e];
            int bin = d & (NBIN - 1);
            int r = atomicAdd(&h2[bin], 1);
            ebuf[basel[bin] + r] = make_int2(s, d);
        }
    }
}

// ---------------- pass 2: exact grouping by node; also zeroes flag[] and n2 ----------------
__global__ __launch_bounds__(256) void k_group(const int2* __restrict__ ebuf,
                                               const int* __restrict__ binbase,
                                               const int* __restrict__ z,
                                               int* __restrict__ csr_src,
                                               int* __restrict__ csr_zoff,
                                               int* __restrict__ start, int* __restrict__ deg,
                                               int* __restrict__ flag, int* __restrict__ n2,
                                               int n_nodes) {
    __shared__ int hh[MAXHI];
    __shared__ int cur[MAXHI];
    __shared__ int wtot[4];
    int k = blockIdx.x, t = threadIdx.x;
    if (k == 0 && t == 0) n2[0] = 0;
    int rs = binbase[k], re = binbase[k + 1];
#pragma unroll
    for (int j = 0; j < MAXHI / 256; ++j) hh[t + j * 256] = 0;
    __syncthreads();
    for (int i = rs + t; i < re; i += 256)
        atomicAdd(&hh[ebuf[i].y >> 9], 1);
    __syncthreads();
    int idx = t * 4;
    int a0 = hh[idx], a1 = hh[idx + 1], a2 = hh[idx + 2], a3 = hh[idx + 3];
    int excl = block_scan_excl(a0 + a1 + a2 + a3, t, wtot, nullptr);
    int e0 = excl, e1 = e0 + a0, e2 = e1 + a1, e3 = e2 + a2;
    cur[idx] = e0; cur[idx + 1] = e1; cur[idx + 2] = e2; cur[idx + 3] = e3;
    int ee[4] = {e0, e1, e2, e3};
    int aa[4] = {a0, a1, a2, a3};
#pragma unroll
    for (int j = 0; j < 4; ++j) {
        int node = ((idx + j) << 9) | k;
        if (node < n_nodes) {
            start[node] = rs + ee[j];
            deg[node] = aa[j];
            flag[node] = 0;
        }
    }
    __syncthreads();
    for (int i = rs + t; i < re; i += 256) {
        int2 sd = ebuf[i];
        int r = rs + atomicAdd(&cur[sd.y >> 9], 1);
        csr_src[r] = sd.x;
        csr_zoff[r] = z[sd.x] << 9;
    }
}

// ---------------- center search + flag sel nodes and their edge sources ----------------
__global__ void k_centerflag(const int* __restrict__ batch, const int* __restrict__ start,
                             const int* __restrict__ deg, const int* __restrict__ csr_src,
                             int* __restrict__ sel, int* __restrict__ flag,
                             int n_nodes, int n_graphs) {
    int g = blockIdx.x;
    if (g >= n_graphs) return;
    int lane = threadIdx.x;   // 64
    int lo = 0, hi = n_nodes;
    while (lo < hi) {
        int mid = (lo + hi) >> 1;
        if (batch[mid] < g) lo = mid + 1;
        else hi = mid;
    }
    int s0 = min(lo, n_nodes - 1);       // JAX index clamp semantics
    int s1 = min(lo + 1, n_nodes - 1);
    if (lane == 0) { sel[2 * g] = s0; sel[2 * g + 1] = s1; flag[s0] = 1; flag[s1] = 1; }
    int a = start[s0], e = a + deg[s0];
    for (int i = a + lane; i < e; i += 64) flag[csr_src[i]] = 1;
    a = start[s1]; e = a + deg[s1];
    for (int i = a + lane; i < e; i += 64) flag[csr_src[i]] = 1;
}

// ---------------- flag -> remap + compact list, single pass (wave scan + atomic base) ----
// nodes2 order is nondeterministic across calls, but output is invariant to it.
__global__ void k_flagcount(const int* __restrict__ flag, int* __restrict__ remap,
                            int* __restrict__ nodes2, int* __restrict__ n2, int n) {
    int i = blockIdx.x * blockDim.x + threadIdx.x;
    int lane = threadIdx.x & 63;
    int f = (i < n) ? flag[i] : 0;
    int incl = f;
#pragma unroll
    for (int off = 1; off < 64; off <<= 1) {
        int u = __shfl_up(incl, off);
        if (lane >= off) incl += u;
    }
    int wsum = __shfl(incl, 63);
    int base = 0;
    if (lane == 63) base = atomicAdd(n2, wsum);
    base = __shfl(base, 63);
    int pos = base + incl - f;
    if (i < n) {
        remap[i] = pos;
        if (f) nodes2[pos] = i;
    }
}

// ---------------- mean aggregation: persistent waves, one wave per row ----------------
// MODE 1 (layer-1 fused): node=r, gather zl via csr_zoff; epilogue +zr[z[node]] & relu -> x1.
// MODE 2 (layer-2 compact): node=idxmap[r]=nodes2[r], gather x via csr_src, out compact.
template<int MODE>
__global__ __launch_bounds__(256) void k_agg(const float* __restrict__ xv_,
                      float* __restrict__ aggout,
                      const int* __restrict__ start, const int* __restrict__ deg,
                      const int* __restrict__ csr_src, const int* __restrict__ csr_zoff,
                      const int* __restrict__ idxmap,
                      const int* __restrict__ z, const float* __restrict__ zr,
                      int n_host, const int* __restrict__ n_dev) {
    int nw_total = gridDim.x * 4;
    int w0 = blockIdx.x * 4 + (threadIdx.x >> 6);
    int lane = threadIdx.x & 63;
    int n = n_dev ? *n_dev : n_host;
    int half = lane >> 5;
    int col = lane & 31;
    const float4* xv = (const float4*)xv_;
    const char* xc = (const char*)xv_;
    for (int r = w0; r < n; r += nw_total) {
        int node = (MODE == 1) ? r : idxmap[r];
        int s = start[node];
        int dg = deg[node];
        int e = s + dg;
        float4 a0 = {0.f,0.f,0.f,0.f}, a1 = {0.f,0.f,0.f,0.f};
        float4 a2 = {0.f,0.f,0.f,0.f}, a3 = {0.f,0.f,0.f,0.f};
        int i = s + half;
        if (MODE == 1) {
            for (; i + 6 < e; i += 8) {   // 4 rows in flight per half-wave
                int o0 = csr_zoff[i];
                int o1 = csr_zoff[i + 2];
                int o2 = csr_zoff[i + 4];
                int o3 = csr_zoff[i + 6];
                float4 v0 = *(const float4*)(xc + o0 + col * 16);
                float4 v1 = *(const float4*)(xc + o1 + col * 16);
                float4 v2 = *(const float4*)(xc + o2 + col * 16);
                float4 v3 = *(const float4*)(xc + o3 + col * 16);
                a0.x += v0.x; a0.y += v0.y; a0.z += v0.z; a0.w += v0.w;
                a1.x += v1.x; a1.y += v1.y; a1.z += v1.z; a1.w += v1.w;
                a2.x += v2.x; a2.y += v2.y; a2.z += v2.z; a2.w += v2.w;
                a3.x += v3.x; a3.y += v3.y; a3.z += v3.z; a3.w += v3.w;
            }
            for (; i < e; i += 2) {
                float4 v0 = *(const float4*)(xc + csr_zoff[i] + col * 16);
                a0.x += v0.x; a0.y += v0.y; a0.z += v0.z; a0.w += v0.w;
            }
        } else {
            for (; i + 6 < e; i += 8) {
                int s0 = csr_src[i];
                int s1 = csr_src[i + 2];
                int s2 = csr_src[i + 4];
                int s3 = csr_src[i + 6];
                float4 v0 = xv[(size_t)s0 * 32 + col];
                float4 v1 = xv[(size_t)s1 * 32 + col];
                float4 v2 = xv[(size_t)s2 * 32 + col];
                float4 v3 = xv[(size_t)s3 * 32 + col];
                a0.x += v0.x; a0.y += v0.y; a0.z += v0.z; a0.w += v0.w;
                a1.x += v1.x; a1.y += v1.y; a1.z += v1.z; a1.w += v1.w;
                a2.x += v2.x; a2.y += v2.y; a2.z += v2.z; a2.w += v2.w;
                a3.x += v3.x; a3.y += v3.y; a3.z += v3.z; a3.w += v3.w;
            }
            for (; i < e; i += 2) {
                float4 v0 = xv[(size_t)csr_src[i] * 32 + col];
                a0.x += v0.x; a0.y += v0.y; a0.z += v0.z; a0.w += v0.w;
            }
        }
        a0.x += a1.x + a2.x + a3.x;
        a0.y += a1.y + a2.y + a3.y;
        a0.z += a1.z + a2.z + a3.z;
        a0.w += a1.w + a2.w + a3.w;
        a0.x += __shfl_xor(a0.x, 32);
        a0.y += __shfl_xor(a0.y, 32);
        a0.z += __shfl_xor(a0.z, 32);
        a0.w += __shfl_xor(a0.w, 32);
        if (half == 0) {
            float di = 1.0f / fmaxf((float)dg, 1.0f);
            float4 o = make_float4(a0.x * di, a0.y * di, a0.z * di, a0.w * di);
            if (MODE == 1) {
                int zn = z[node];
                float4 rv = ((const float4*)zr)[(size_t)zn * 32 + col];
                o.x = fmaxf(o.x + rv.x, 0.f);
                o.y = fmaxf(o.y + rv.y, 0.f);
                o.z = fmaxf(o.z + rv.z, 0.f);
                o.w = fmaxf(o.w + rv.w, 0.f);
            }
            ((float4*)aggout)[(size_t)r * 32 + col] = o;
        }
    }
}

// ---------------- fused layer GEMM via split-bf16 MFMA (layer 2) ----------------
__global__ __launch_bounds__(256) void k_gemm(const float* __restrict__ aggsrc,
                                              const float* __restrict__ xsrc,
                                              float* __restrict__ out,
                                              const unsigned short* __restrict__ wh,
                                              const unsigned short* __restrict__ wlo,
                                              const float* __restrict__ bias,
                                              const int* __restrict__ xidx,
                                              int n_host, const int* __restrict__ n_dev,
                                              int do_relu) {
    __shared__ unsigned int sAh[GM * 16], sAl[GM * 16];
    __shared__ unsigned int sBh[HID * 16], sBl[HID * 16];
    int n_rows = n_dev ? *n_dev : n_host;
    int t = threadIdx.x;
    int node0 = blockIdx.x * GM;
    if (node0 >= n_rows) return;
    int wv = t >> 6, lane = t & 63;
    int lrow = lane & 15, lk = lane >> 4;

    f32x4 acc[2][8];
#pragma unroll
    for (int m = 0; m < 2; ++m)
#pragma unroll
        for (int n = 0; n < 8; ++n) acc[m][n] = (f32x4){0.f, 0.f, 0.f, 0.f};

    int srow = t >> 2;      // 0..63 (+64 for rr=1)
    int sq = t & 3;         // quarter of the 32-k row

    int gg[2] = {node0 + srow, node0 + srow + 64};
    bool vv[2] = {gg[0] < n_rows, gg[1] < n_rows};
    int xr[2];
#pragma unroll
    for (int rr = 0; rr < 2; ++rr)
        xr[rr] = xidx ? (vv[rr] ? xidx[gg[rr]] : 0) : gg[rr];

    for (int c = 0; c < 8; ++c) {
        int kbase = (c & 3) * 32;
        int kb = c * 32;
        // --- stage A: 128 rows x 32 k, fp32 -> split bf16 hi/lo ---
#pragma unroll
        for (int rr = 0; rr < 2; ++rr) {
            int row = srow + rr * 64;
            const float* srcrow = (c < 4) ? aggsrc + (size_t)gg[rr] * HID
                                          : xsrc + (size_t)xr[rr] * HID;
            float f[8];
            if (vv[rr]) {
                const float4* rp = (const float4*)(srcrow + kbase + sq * 8);
                float4 v0 = rp[0], v1 = rp[1];
                f[0]=v0.x; f[1]=v0.y; f[2]=v0.z; f[3]=v0.w;
                f[4]=v1.x; f[5]=v1.y; f[6]=v1.z; f[7]=v1.w;
            } else {
#pragma unroll
                for (int j = 0; j < 8; ++j) f[j] = 0.f;
            }
            unsigned int h[4], l[4];
#pragma unroll
            for (int j = 0; j < 4; ++j) {
                unsigned short h0 = f2bf(f[2*j]), h1 = f2bf(f[2*j+1]);
                unsigned short l0 = f2bf(f[2*j] - bf2f(h0));
                unsigned short l1 = f2bf(f[2*j+1] - bf2f(h1));
                h[j] = pack2(h0, h1);
                l[j] = pack2(l0, l1);
            }
            unsigned int base = row * 16 + sq * 4;
            *(uint4*)&sAh[base] = make_uint4(h[0], h[1], h[2], h[3]);
            *(uint4*)&sAl[base] = make_uint4(l[0], l[1], l[2], l[3]);
        }
        // --- stage B: 128 d-rows x 32 k, bf16 copy ---
#pragma unroll
        for (int rr = 0; rr < 2; ++rr) {
            int d = srow + rr * 64;
            size_t go = (size_t)d * 256 + kb + sq * 8;
            uint4 vh = *(const uint4*)(wh + go);
            uint4 vl = *(const uint4*)(wlo + go);
            unsigned int base = d * 16 + sq * 4;
            *(uint4*)&sBh[base] = vh;
            *(uint4*)&sBl[base] = vl;
        }
        __syncthreads();
        // --- compute: 2 M-tiles x 8 N-tiles x 3 split products ---
        bf16x8 ah0, al0, ah1, al1;
        {
            unsigned int a0 = (unsigned)(wv * 32 + lrow) * 16 + lk * 4;
            unsigned int a1 = (unsigned)(wv * 32 + 16 + lrow) * 16 + lk * 4;
            ah0 = ld_frag(&sAh[a0]); al0 = ld_frag(&sAl[a0]);
            ah1 = ld_frag(&sAh[a1]); al1 = ld_frag(&sAl[a1]);
        }
#pragma unroll
        for (int n = 0; n < 8; ++n) {
            unsigned int b = (unsigned)(n * 16 + lrow) * 16 + lk * 4;
            bf16x8 bh = ld_frag(&sBh[b]);
            bf16x8 bl = ld_frag(&sBl[b]);
            acc[0][n] = __builtin_amdgcn_mfma_f32_16x16x32_bf16(ah0, bh, acc[0][n], 0, 0, 0);
            acc[0][n] = __builtin_amdgcn_mfma_f32_16x16x32_bf16(al0, bh, acc[0][n], 0, 0, 0);
            acc[0][n] = __builtin_amdgcn_mfma_f32_16x16x32_bf16(ah0, bl, acc[0][n], 0, 0, 0);
            acc[1][n] = __builtin_amdgcn_mfma_f32_16x16x32_bf16(ah1, bh, acc[1][n], 0, 0, 0);
            acc[1][n] = __builtin_amdgcn_mfma_f32_16x16x32_bf16(al1, bh, acc[1][n], 0, 0, 0);
            acc[1][n] = __builtin_amdgcn_mfma_f32_16x16x32_bf16(ah1, bl, acc[1][n], 0, 0, 0);
        }
        __syncthreads();
    }
    // --- epilogue: bias + relu + store (D: col=lane&15, row=(lane>>4)*4+reg) ---
#pragma unroll
    for (int m = 0; m < 2; ++m) {
        int rbase = node0 + wv * 32 + m * 16 + lk * 4;
#pragma unroll
        for (int n = 0; n < 8; ++n) {
            int colb = n * 16 + lrow;
            float bb = bias[colb];
#pragma unroll
            for (int r = 0; r < 4; ++r) {
                int row = rbase + r;
                if (row < n_rows) {
                    float v = acc[m][n][r] + bb;
                    if (do_relu) v = fmaxf(v, 0.f);
                    out[(size_t)row * HID + colb] = v;
                }
            }
        }
    }
}

// ---------------- fused tail: layer-3 (2 rows/graph, fp32 VALU) + product head ----------------
__global__ __launch_bounds__(256) void k_tail(const float* __restrict__ x2c,
                                              const int* __restrict__ sel,
                                              const int* __restrict__ remap,
                                              const int* __restrict__ start,
                                              const int* __restrict__ deg,
                                              const int* __restrict__ csr_src,
                                              const float* __restrict__ Wl3,
                                              const float* __restrict__ Wr3,
                                              const float* __restrict__ b3,
                                              const float* __restrict__ w1,
                                              const float* __restrict__ b1,
                                              const float* __restrict__ w2,
                                              const float* __restrict__ b2,
                                              float* __restrict__ out, int n_graphs) {
    int g = blockIdx.x;
    if (g >= n_graphs) return;
    __shared__ float sagg[2][HID];
    __shared__ float sxs[2][HID];
    __shared__ float stmp[2][HID];
    __shared__ float sy[2][HID];
    __shared__ float sh[HID];
    __shared__ float sh2[HID];
    int t = threadIdx.x;
    int wv = t >> 6, lane = t & 63;
    int r = wv >> 1;       // node slot 0/1
    int par = wv & 1;      // edge parity within slot
    int node = sel[2 * g + r];
    int s = start[node], dgr = deg[node], e = s + dgr;
    float2 acc = {0.f, 0.f};
    for (int i = s + par; i < e; i += 2) {
        int sr = remap[csr_src[i]];
        float2 v = ((const float2*)x2c)[(size_t)sr * 64 + lane];
        acc.x += v.x; acc.y += v.y;
    }
    if (par == 1) { stmp[r][2 * lane] = acc.x; stmp[r][2 * lane + 1] = acc.y; }
    __syncthreads();
    if (par == 0) {
        float di = 1.0f / fmaxf((float)dgr, 1.0f);
        sagg[r][2 * lane]     = (acc.x + stmp[r][2 * lane]) * di;
        sagg[r][2 * lane + 1] = (acc.y + stmp[r][2 * lane + 1]) * di;
        int xr = remap[node];
        float2 xv = ((const float2*)x2c)[(size_t)xr * 64 + lane];
        sxs[r][2 * lane] = xv.x; sxs[r][2 * lane + 1] = xv.y;
    }
    __syncthreads();
    // y[r][d] = dot(sagg[r], Wl3[d]) + dot(sxs[r], Wr3[d]) + b3[d]
    {
        int r2 = t >> 7;
        int d = t & 127;
        const float4* wl = (const float4*)(Wl3 + (size_t)d * HID);
        const float4* wr = (const float4*)(Wr3 + (size_t)d * HID);
        float a = 0.f;
#pragma unroll 8
        for (int k4 = 0; k4 < HID / 4; ++k4) {
            float4 w = wl[k4];
            float4 v = *(const float4*)&sagg[r2][k4 * 4];
            a += w.x * v.x + w.y * v.y + w.z * v.z + w.w * v.w;
            float4 w2v = wr[k4];
            float4 x = *(const float4*)&sxs[r2][k4 * 4];
            a += w2v.x * x.x + w2v.y * x.y + w2v.z * x.z + w2v.w * x.w;
        }
        sy[r2][d] = a + b3[d];
    }
    __syncthreads();
    if (t < HID) sh[t] = sy[0][t] * sy[1][t];
    __syncthreads();
    if (t < HID) {
        const float4* wr1 = (const float4*)(w1 + (size_t)t * HID);
        float a = b1[t];
#pragma unroll 8
        for (int k4 = 0; k4 < HID / 4; ++k4) {
            float4 w = wr1[k4];
            float4 h = *(const float4*)&sh[k4 * 4];
            a += w.x * h.x + w.y * h.y + w.z * h.z + w.w * h.w;
        }
        sh2[t] = fmaxf(a, 0.f) * w2[t];
    }
    __syncthreads();
    if (wv == 0) {
        float p = sh2[lane] + sh2[lane + 64];
#pragma unroll
        for (int off = 32; off > 0; off >>= 1) p += __shfl_down(p, off);
        if (lane == 0) out[g] = p + b2[0];
    }
}

extern "C" void kernel_launch(void* const* d_in, const int* in_sizes, int n_in,
                              void* d_out, int out_size, void* d_ws, size_t ws_size,
                              hipStream_t stream) {
    const int* z = (const int*)d_in[0];
    const int* edge_index = (const int*)d_in[1];
    const int* batch = (const int*)d_in[2];
    const float* z_emb = (const float*)d_in[4];
    const float* Wl = (const float*)d_in[5];
    const float* bl = (const float*)d_in[6];
    const float* Wr = (const float*)d_in[7];
    const float* lin1_w = (const float*)d_in[8];
    const float* lin1_b = (const float*)d_in[9];
    const float* lin2_w = (const float*)d_in[10];
    const float* lin2_b = (const float*)d_in[11];
    float* out = (float*)d_out;

    int n_nodes = in_sizes[0];
    int n_edges = in_sizes[1] / 2;
    int max_z = in_sizes[4] / HID;   // z_emb rows
    int n_graphs = out_size;         // output is [n_graphs, 1]

    const int* e_src = edge_index;
    const int* e_dst = edge_index + n_edges;

    char* p = (char*)d_ws;
    auto alloc = [&](size_t bytes) {
        char* r = p;
        p += (bytes + 511) & ~(size_t)511;
        return r;
    };
    float* x       = (float*)alloc((size_t)n_nodes * HID * 4);   // x1 (full)
    float* agg2    = (float*)alloc((size_t)n_nodes * HID * 4);   // layer-2 agg, compact
    float* x2c     = (float*)alloc((size_t)n_nodes * HID * 4);   // x2, compact
    int*   deg     = (int*)alloc((size_t)n_nodes * 4);
    int*   start   = (int*)alloc((size_t)n_nodes * 4);
    int2*  ebuf    = (int2*)alloc((size_t)n_edges * 8);
    int*   csr_src = (int*)alloc((size_t)n_edges * 4);
    int*   csr_zoff= (int*)alloc((size_t)n_edges * 4);
    int B = (n_edges + CHUNK - 1) / CHUNK;
    int*   hist     = (int*)alloc((size_t)B * NBIN * 4);
    int*   bintotal = (int*)alloc((size_t)NBIN * 4);
    int*   binbase  = (int*)alloc((size_t)(NBIN + 1) * 4);
    int*   done     = (int*)alloc(4);
    int*   sel    = (int*)alloc((size_t)(2 * n_graphs) * 4);
    int*   flag   = (int*)alloc((size_t)n_nodes * 4);
    int*   remap  = (int*)alloc((size_t)n_nodes * 4);
    int*   nodes2 = (int*)alloc((size_t)n_nodes * 4);
    int*   n2     = (int*)alloc(4);
    float* zl     = (float*)alloc((size_t)max_z * HID * 4);
    float* zr     = (float*)alloc((size_t)max_z * HID * 4);
    unsigned short* wh  = (unsigned short*)alloc((size_t)3 * HID * 2 * HID * 2);
    unsigned short* wlo = (unsigned short*)alloc((size_t)3 * HID * 2 * HID * 2);

    int wsplit_blocks = (3 * HID * 2 * HID + 255) / 256;
    k_prep<<<max_z + wsplit_blocks, 256, 0, stream>>>(z_emb, Wl, Wr, bl, zl, zr,
                                                      wh, wlo, done, max_z);

    // ---- atomic-free CSR build: 2-level counting sort (4 dispatches) ----
    k_hist<<<B, 256, 0, stream>>>(e_dst, hist, n_edges);
    k_colscan<<<NBIN, 256, 0, stream>>>(hist, bintotal, binbase, done, B);
    k_route<<<B, 256, 0, stream>>>(e_src, e_dst, hist, binbase, ebuf, n_edges);
    k_group<<<NBIN, 256, 0, stream>>>(ebuf, binbase, z, csr_src, csr_zoff,
                                      start, deg, flag, n2, n_nodes);

    // reachability for layer-2: sel ∪ srcs(sel edges), then compact
    k_centerflag<<<n_graphs, 64, 0, stream>>>(batch, start, deg, csr_src, sel, flag,
                                              n_nodes, n_graphs);
    k_flagcount<<<(n_nodes + 255) / 256, 256, 0, stream>>>(flag, remap, nodes2, n2, n_nodes);

    int agg_blocks = (n_nodes + 3) / 4;
    // layer 1 (full, fused): x1 = relu(deginv * sum(zl[z_src]) + zr[z[node]])
    k_agg<1><<<agg_blocks, 256, 0, stream>>>(zl, x, start, deg, csr_src, csr_zoff,
                                             nullptr, z, zr, n_nodes, nullptr);
    // layer 2 (compact over nodes2): persistent-stride waves, device row count
    k_agg<2><<<2048, 256, 0, stream>>>(x, agg2, start, deg, csr_src, nullptr, nodes2,
                                       nullptr, nullptr, 0, n2);
    k_gemm<<<(n_nodes + GM - 1) / GM, 256, 0, stream>>>(agg2, x, x2c,
                                            wh + (size_t)HID * 2 * HID,
                                            wlo + (size_t)HID * 2 * HID,
                                            bl + HID, nodes2, 0, n2, 1);
    // layer 3 + head, fused (fp32)
    k_tail<<<n_graphs, 256, 0, stream>>>(x2c, sel, remap, start, deg, csr_src,
                                         Wl + (size_t)2 * HID * HID,
                                         Wr + (size_t)2 * HID * HID,
                                         bl + (size_t)2 * HID,
                                         lin1_w, lin1_b, lin2_w, lin2_b,
                                         out, n_graphs);
}

// Round 13
// 275.243 us; speedup vs baseline: 1.0588x; 1.0588x over previous
//
#include <hip/hip_runtime.h>
#include <hip/hip_bf16.h>
#include <cstdint>

#define HID 128
#define GM 128          // rows per GEMM block
#define NBIN 512        // low-9-bit buckets
#define CHUNK 2048      // edges per histogram/route block
#define MAXHI 1024      // max (n_nodes/NBIN) supported

typedef __attribute__((ext_vector_type(8))) short bf16x8;
typedef __attribute__((ext_vector_type(4))) float f32x4;

__device__ __forceinline__ unsigned short f2bf(float f) {
    union { __hip_bfloat16 h; unsigned short u; } c;
    c.h = __float2bfloat16(f);
    return c.u;
}
__device__ __forceinline__ float bf2f(unsigned short u) {
    union { unsigned int i; float f; } c;
    c.i = ((unsigned int)u) << 16;
    return c.f;
}
__device__ __forceinline__ unsigned int pack2(unsigned short a, unsigned short b) {
    return (unsigned int)a | ((unsigned int)b << 16);
}
__device__ __forceinline__ bf16x8 ld_frag(const unsigned int* p) {
    union { uint4 u; bf16x8 f; } c;
    c.u = *(const uint4*)p;
    return c.f;
}

// exclusive block scan over 256 threads (wave shfl + LDS wave totals).
__device__ __forceinline__ int block_scan_excl(int v, int t, int* wtot, int* tot) {
    int lane = t & 63, wv = t >> 6;
    int incl = v;
#pragma unroll
    for (int off = 1; off < 64; off <<= 1) {
        int u = __shfl_up(incl, off);
        if (lane >= off) incl += u;
    }
    if (lane == 63) wtot[wv] = incl;
    __syncthreads();
    int woff = 0;
    for (int w = 0; w < wv; ++w) woff += wtot[w];
    if (tot) *tot = wtot[0] + wtot[1] + wtot[2] + wtot[3];
    __syncthreads();   // allow wtot reuse
    return woff + incl - v;
}

// ---------------- fused prep: zl/zr tables (blocks < max_z) + W split (rest) ----------------
__global__ void k_prep(const float* __restrict__ z_emb, const float* __restrict__ Wl,
                       const float* __restrict__ Wr, const float* __restrict__ bl,
                       float* __restrict__ zl, float* __restrict__ zr,
                       unsigned short* __restrict__ wh, unsigned short* __restrict__ wlo,
                       int max_z) {
    int t = threadIdx.x;
    if ((int)blockIdx.x < max_z) {
        __shared__ float row[HID];
        int r = blockIdx.x;
        if (t < HID) row[t] = z_emb[(size_t)r * HID + t];
        __syncthreads();
        int d = t & 127;
        const float* w = (t < 128 ? Wl : Wr) + (size_t)d * HID;
        float acc = 0.f;
#pragma unroll
        for (int k4 = 0; k4 < HID / 4; ++k4) {
            float4 wv = *(const float4*)(w + k4 * 4);
            float4 hv = *(const float4*)&row[k4 * 4];
            acc += wv.x * hv.x + wv.y * hv.y + wv.z * hv.z + wv.w * hv.w;
        }
        if (t < 128) zl[(size_t)r * HID + d] = acc;
        else         zr[(size_t)r * HID + d] = acc + bl[d];
    } else {
        int idx = (blockIdx.x - max_z) * 256 + t;
        if (idx >= 3 * HID * 2 * HID) return;
        int l = idx / (HID * 2 * HID);
        int r = idx - l * (HID * 2 * HID);
        int d = r >> 8;
        int k = r & 255;
        float v = (k < HID) ? Wl[((size_t)l * HID + d) * HID + k]
                            : Wr[((size_t)l * HID + d) * HID + (k - HID)];
        unsigned short h = f2bf(v);
        unsigned short lo = f2bf(v - bf2f(h));
        wh[idx] = h;
        wlo[idx] = lo;
    }
}

// ---------------- pass 1a: per-block 512-bin histogram of dst low bits ----------------
__global__ __launch_bounds__(256) void k_hist(const int* __restrict__ dst,
                                              int* __restrict__ hist, int n_edges) {
    __shared__ int h[NBIN];
    int t = threadIdx.x;
    h[t] = 0; h[t + 256] = 0;
    __syncthreads();
    int base = blockIdx.x * CHUNK;
#pragma unroll
    for (int j = 0; j < CHUNK / 256; ++j) {
        int e = base + j * 256 + t;
        if (e < n_edges) atomicAdd(&h[dst[e] & (NBIN - 1)], 1);
    }
    __syncthreads();
    hist[(size_t)blockIdx.x * NBIN + t] = h[t];
    hist[(size_t)blockIdx.x * NBIN + t + 256] = h[t + 256];
}

// ---------------- pass 1b: per-bin exclusive scan over blocks (in place; plain stores) ----
__global__ __launch_bounds__(256) void k_colscan(int* __restrict__ hist,
                                                 int* __restrict__ bintotal, int B) {
    __shared__ int wtot[4];
    int k = blockIdx.x, t = threadIdx.x;
    int run = 0;
    for (int base = 0; base < B; base += 256) {
        int b = base + t;
        int v = (b < B) ? hist[(size_t)b * NBIN + k] : 0;
        int tot;
        int excl = block_scan_excl(v, t, wtot, &tot);
        if (b < B) hist[(size_t)b * NBIN + k] = run + excl;
        run += tot;
    }
    if (t == 0) bintotal[k] = run;
}

// ---------------- pass 1c: exclusive scan of 512 bin totals ----------------
__global__ __launch_bounds__(256) void k_binbase(const int* __restrict__ bintotal,
                                                 int* __restrict__ binbase) {
    __shared__ int wtot[4];
    int t = threadIdx.x;
    int a0 = bintotal[2 * t], a1 = bintotal[2 * t + 1];
    int excl = block_scan_excl(a0 + a1, t, wtot, nullptr);
    binbase[2 * t] = excl;
    binbase[2 * t + 1] = excl + a0;
    if (t == 255) binbase[NBIN] = excl + a0 + a1;
}

// ---------------- pass 1d: route edges into bin regions (LDS ranks, no global atomics) --
__global__ __launch_bounds__(256) void k_route(const int* __restrict__ src,
                                               const int* __restrict__ dst,
                                               const int* __restrict__ histex,
                                               const int* __restrict__ binbase,
                                               int2* __restrict__ ebuf, int n_edges) {
    __shared__ int h2[NBIN];
    __shared__ int basel[NBIN];
    int t = threadIdx.x;
    h2[t] = 0; h2[t + 256] = 0;
    basel[t]       = binbase[t]       + histex[(size_t)blockIdx.x * NBIN + t];
    basel[t + 256] = binbase[t + 256] + histex[(size_t)blockIdx.x * NBIN + t + 256];
    __syncthreads();
    int base = blockIdx.x * CHUNK;
#pragma unroll
    for (int j = 0; j < CHUNK / 256; ++j) {
        int e = base + j * 256 + t;
        if (e < n_edges) {
            int d = dst[e], s = src[e];
            int bin = d & (NBIN - 1);
            int r = atomicAdd(&h2[bin], 1);
            ebuf[basel[bin] + r] = make_int2(s, d);
        }
    }
}

// ---------------- pass 2: exact grouping by node; also zeroes flag[] and n2 ----------------
__global__ __launch_bounds__(256) void k_group(const int2* __restrict__ ebuf,
                                               const int* __restrict__ binbase,
                                               const int* __restrict__ z,
                                               int* __restrict__ csr_src,
                                               int* __restrict__ csr_zoff,
                                               int* __restrict__ start, int* __restrict__ deg,
                                               int* __restrict__ flag, int* __restrict__ n2,
                                               int n_nodes) {
    __shared__ int hh[MAXHI];
    __shared__ int cur[MAXHI];
    __shared__ int wtot[4];
    int k = blockIdx.x, t = threadIdx.x;
    if (k == 0 && t == 0) n2[0] = 0;
    int rs = binbase[k], re = binbase[k + 1];
#pragma unroll
    for (int j = 0; j < MAXHI / 256; ++j) hh[t + j * 256] = 0;
    __syncthreads();
    for (int i = rs + t; i < re; i += 256)
        atomicAdd(&hh[ebuf[i].y >> 9], 1);
    __syncthreads();
    int idx = t * 4;
    int a0 = hh[idx], a1 = hh[idx + 1], a2 = hh[idx + 2], a3 = hh[idx + 3];
    int excl = block_scan_excl(a0 + a1 + a2 + a3, t, wtot, nullptr);
    int e0 = excl, e1 = e0 + a0, e2 = e1 + a1, e3 = e2 + a2;
    cur[idx] = e0; cur[idx + 1] = e1; cur[idx + 2] = e2; cur[idx + 3] = e3;
    int ee[4] = {e0, e1, e2, e3};
    int aa[4] = {a0, a1, a2, a3};
#pragma unroll
    for (int j = 0; j < 4; ++j) {
        int node = ((idx + j) << 9) | k;
        if (node < n_nodes) {
            start[node] = rs + ee[j];
            deg[node] = aa[j];
            flag[node] = 0;
        }
    }
    __syncthreads();
    for (int i = rs + t; i < re; i += 256) {
        int2 sd = ebuf[i];
        int r = rs + atomicAdd(&cur[sd.y >> 9], 1);
        csr_src[r] = sd.x;
        csr_zoff[r] = z[sd.x] << 9;
    }
}

// ---------------- center search + flag sel nodes and their edge sources ----------------
__global__ void k_centerflag(const int* __restrict__ batch, const int* __restrict__ start,
                             const int* __restrict__ deg, const int* __restrict__ csr_src,
                             int* __restrict__ sel, int* __restrict__ flag,
                             int n_nodes, int n_graphs) {
    int g = blockIdx.x;
    if (g >= n_graphs) return;
    int lane = threadIdx.x;   // 64
    int lo = 0, hi = n_nodes;
    while (lo < hi) {
        int mid = (lo + hi) >> 1;
        if (batch[mid] < g) lo = mid + 1;
        else hi = mid;
    }
    int s0 = min(lo, n_nodes - 1);       // JAX index clamp semantics
    int s1 = min(lo + 1, n_nodes - 1);
    if (lane == 0) { sel[2 * g] = s0; sel[2 * g + 1] = s1; flag[s0] = 1; flag[s1] = 1; }
    int a = start[s0], e = a + deg[s0];
    for (int i = a + lane; i < e; i += 64) flag[csr_src[i]] = 1;
    a = start[s1]; e = a + deg[s1];
    for (int i = a + lane; i < e; i += 64) flag[csr_src[i]] = 1;
}

// ---------------- flag -> remap + compact list, single pass (wave scan + atomic base) ----
// nodes2 order is nondeterministic across calls, but output is invariant to it.
__global__ void k_flagcount(const int* __restrict__ flag, int* __restrict__ remap,
                            int* __restrict__ nodes2, int* __restrict__ n2, int n) {
    int i = blockIdx.x * blockDim.x + threadIdx.x;
    int lane = threadIdx.x & 63;
    int f = (i < n) ? flag[i] : 0;
    int incl = f;
#pragma unroll
    for (int off = 1; off < 64; off <<= 1) {
        int u = __shfl_up(incl, off);
        if (lane >= off) incl += u;
    }
    int wsum = __shfl(incl, 63);
    int base = 0;
    if (lane == 63) base = atomicAdd(n2, wsum);
    base = __shfl(base, 63);
    int pos = base + incl - f;
    if (i < n) {
        remap[i] = pos;
        if (f) nodes2[pos] = i;
    }
}

// ---------------- mean aggregation: persistent waves, one wave per row ----------------
// MODE 1 (layer-1 fused): node=r, gather zl via csr_zoff; epilogue +zr[z[node]] & relu -> x1.
// MODE 2 (layer-2 compact): node=idxmap[r]=nodes2[r], gather x via csr_src, out compact.
template<int MODE>
__global__ __launch_bounds__(256) void k_agg(const float* __restrict__ xv_,
                      float* __restrict__ aggout,
                      const int* __restrict__ start, const int* __restrict__ deg,
                      const int* __restrict__ csr_src, const int* __restrict__ csr_zoff,
                      const int* __restrict__ idxmap,
                      const int* __restrict__ z, const float* __restrict__ zr,
                      int n_host, const int* __restrict__ n_dev) {
    int nw_total = gridDim.x * 4;
    int w0 = blockIdx.x * 4 + (threadIdx.x >> 6);
    int lane = threadIdx.x & 63;
    int n = n_dev ? *n_dev : n_host;
    int half = lane >> 5;
    int col = lane & 31;
    const float4* xv = (const float4*)xv_;
    const char* xc = (const char*)xv_;
    for (int r = w0; r < n; r += nw_total) {
        int node = (MODE == 1) ? r : idxmap[r];
        int s = start[node];
        int dg = deg[node];
        int e = s + dg;
        float4 a0 = {0.f,0.f,0.f,0.f}, a1 = {0.f,0.f,0.f,0.f};
        float4 a2 = {0.f,0.f,0.f,0.f}, a3 = {0.f,0.f,0.f,0.f};
        int i = s + half;
        if (MODE == 1) {
            for (; i + 6 < e; i += 8) {   // 4 rows in flight per half-wave
                int o0 = csr_zoff[i];
                int o1 = csr_zoff[i + 2];
                int o2 = csr_zoff[i + 4];
                int o3 = csr_zoff[i + 6];
                float4 v0 = *(const float4*)(xc + o0 + col * 16);
                float4 v1 = *(const float4*)(xc + o1 + col * 16);
                float4 v2 = *(const float4*)(xc + o2 + col * 16);
                float4 v3 = *(const float4*)(xc + o3 + col * 16);
                a0.x += v0.x; a0.y += v0.y; a0.z += v0.z; a0.w += v0.w;
                a1.x += v1.x; a1.y += v1.y; a1.z += v1.z; a1.w += v1.w;
                a2.x += v2.x; a2.y += v2.y; a2.z += v2.z; a2.w += v2.w;
                a3.x += v3.x; a3.y += v3.y; a3.z += v3.z; a3.w += v3.w;
            }
            for (; i < e; i += 2) {
                float4 v0 = *(const float4*)(xc + csr_zoff[i] + col * 16);
                a0.x += v0.x; a0.y += v0.y; a0.z += v0.z; a0.w += v0.w;
            }
        } else {
            for (; i + 6 < e; i += 8) {
                int s0 = csr_src[i];
                int s1 = csr_src[i + 2];
                int s2 = csr_src[i + 4];
                int s3 = csr_src[i + 6];
                float4 v0 = xv[(size_t)s0 * 32 + col];
                float4 v1 = xv[(size_t)s1 * 32 + col];
                float4 v2 = xv[(size_t)s2 * 32 + col];
                float4 v3 = xv[(size_t)s3 * 32 + col];
                a0.x += v0.x; a0.y += v0.y; a0.z += v0.z; a0.w += v0.w;
                a1.x += v1.x; a1.y += v1.y; a1.z += v1.z; a1.w += v1.w;
                a2.x += v2.x; a2.y += v2.y; a2.z += v2.z; a2.w += v2.w;
                a3.x += v3.x; a3.y += v3.y; a3.z += v3.z; a3.w += v3.w;
            }
            for (; i < e; i += 2) {
                float4 v0 = xv[(size_t)csr_src[i] * 32 + col];
                a0.x += v0.x; a0.y += v0.y; a0.z += v0.z; a0.w += v0.w;
            }
        }
        a0.x += a1.x + a2.x + a3.x;
        a0.y += a1.y + a2.y + a3.y;
        a0.z += a1.z + a2.z + a3.z;
        a0.w += a1.w + a2.w + a3.w;
        a0.x += __shfl_xor(a0.x, 32);
        a0.y += __shfl_xor(a0.y, 32);
        a0.z += __shfl_xor(a0.z, 32);
        a0.w += __shfl_xor(a0.w, 32);
        if (half == 0) {
            float di = 1.0f / fmaxf((float)dg, 1.0f);
            float4 o = make_float4(a0.x * di, a0.y * di, a0.z * di, a0.w * di);
            if (MODE == 1) {
                int zn = z[node];
                float4 rv = ((const float4*)zr)[(size_t)zn * 32 + col];
                o.x = fmaxf(o.x + rv.x, 0.f);
                o.y = fmaxf(o.y + rv.y, 0.f);
                o.z = fmaxf(o.z + rv.z, 0.f);
                o.w = fmaxf(o.w + rv.w, 0.f);
            }
            ((float4*)aggout)[(size_t)r * 32 + col] = o;
        }
    }
}

// ---------------- fused layer GEMM via split-bf16 MFMA (layer 2) ----------------
__global__ __launch_bounds__(256) void k_gemm(const float* __restrict__ aggsrc,
                                              const float* __restrict__ xsrc,
                                              float* __restrict__ out,
                                              const unsigned short* __restrict__ wh,
                                              const unsigned short* __restrict__ wlo,
                                              const float* __restrict__ bias,
                                              const int* __restrict__ xidx,
                                              int n_host, const int* __restrict__ n_dev,
                                              int do_relu) {
    __shared__ unsigned int sAh[GM * 16], sAl[GM * 16];
    __shared__ unsigned int sBh[HID * 16], sBl[HID * 16];
    int n_rows = n_dev ? *n_dev : n_host;
    int t = threadIdx.x;
    int node0 = blockIdx.x * GM;
    if (node0 >= n_rows) return;
    int wv = t >> 6, lane = t & 63;
    int lrow = lane & 15, lk = lane >> 4;

    f32x4 acc[2][8];
#pragma unroll
    for (int m = 0; m < 2; ++m)
#pragma unroll
        for (int n = 0; n < 8; ++n) acc[m][n] = (f32x4){0.f, 0.f, 0.f, 0.f};

    int srow = t >> 2;      // 0..63 (+64 for rr=1)
    int sq = t & 3;         // quarter of the 32-k row

    int gg[2] = {node0 + srow, node0 + srow + 64};
    bool vv[2] = {gg[0] < n_rows, gg[1] < n_rows};
    int xr[2];
#pragma unroll
    for (int rr = 0; rr < 2; ++rr)
        xr[rr] = xidx ? (vv[rr] ? xidx[gg[rr]] : 0) : gg[rr];

    for (int c = 0; c < 8; ++c) {
        int kbase = (c & 3) * 32;
        int kb = c * 32;
        // --- stage A: 128 rows x 32 k, fp32 -> split bf16 hi/lo ---
#pragma unroll
        for (int rr = 0; rr < 2; ++rr) {
            int row = srow + rr * 64;
            const float* srcrow = (c < 4) ? aggsrc + (size_t)gg[rr] * HID
                                          : xsrc + (size_t)xr[rr] * HID;
            float f[8];
            if (vv[rr]) {
                const float4* rp = (const float4*)(srcrow + kbase + sq * 8);
                float4 v0 = rp[0], v1 = rp[1];
                f[0]=v0.x; f[1]=v0.y; f[2]=v0.z; f[3]=v0.w;
                f[4]=v1.x; f[5]=v1.y; f[6]=v1.z; f[7]=v1.w;
            } else {
#pragma unroll
                for (int j = 0; j < 8; ++j) f[j] = 0.f;
            }
            unsigned int h[4], l[4];
#pragma unroll
            for (int j = 0; j < 4; ++j) {
                unsigned short h0 = f2bf(f[2*j]), h1 = f2bf(f[2*j+1]);
                unsigned short l0 = f2bf(f[2*j] - bf2f(h0));
                unsigned short l1 = f2bf(f[2*j+1] - bf2f(h1));
                h[j] = pack2(h0, h1);
                l[j] = pack2(l0, l1);
            }
            unsigned int base = row * 16 + sq * 4;
            *(uint4*)&sAh[base] = make_uint4(h[0], h[1], h[2], h[3]);
            *(uint4*)&sAl[base] = make_uint4(l[0], l[1], l[2], l[3]);
        }
        // --- stage B: 128 d-rows x 32 k, bf16 copy ---
#pragma unroll
        for (int rr = 0; rr < 2; ++rr) {
            int d = srow + rr * 64;
            size_t go = (size_t)d * 256 + kb + sq * 8;
            uint4 vh = *(const uint4*)(wh + go);
            uint4 vl = *(const uint4*)(wlo + go);
            unsigned int base = d * 16 + sq * 4;
            *(uint4*)&sBh[base] = vh;
            *(uint4*)&sBl[base] = vl;
        }
        __syncthreads();
        // --- compute: 2 M-tiles x 8 N-tiles x 3 split products ---
        bf16x8 ah0, al0, ah1, al1;
        {
            unsigned int a0 = (unsigned)(wv * 32 + lrow) * 16 + lk * 4;
            unsigned int a1 = (unsigned)(wv * 32 + 16 + lrow) * 16 + lk * 4;
            ah0 = ld_frag(&sAh[a0]); al0 = ld_frag(&sAl[a0]);
            ah1 = ld_frag(&sAh[a1]); al1 = ld_frag(&sAl[a1]);
        }
#pragma unroll
        for (int n = 0; n < 8; ++n) {
            unsigned int b = (unsigned)(n * 16 + lrow) * 16 + lk * 4;
            bf16x8 bh = ld_frag(&sBh[b]);
            bf16x8 bl = ld_frag(&sBl[b]);
            acc[0][n] = __builtin_amdgcn_mfma_f32_16x16x32_bf16(ah0, bh, acc[0][n], 0, 0, 0);
            acc[0][n] = __builtin_amdgcn_mfma_f32_16x16x32_bf16(al0, bh, acc[0][n], 0, 0, 0);
            acc[0][n] = __builtin_amdgcn_mfma_f32_16x16x32_bf16(ah0, bl, acc[0][n], 0, 0, 0);
            acc[1][n] = __builtin_amdgcn_mfma_f32_16x16x32_bf16(ah1, bh, acc[1][n], 0, 0, 0);
            acc[1][n] = __builtin_amdgcn_mfma_f32_16x16x32_bf16(al1, bh, acc[1][n], 0, 0, 0);
            acc[1][n] = __builtin_amdgcn_mfma_f32_16x16x32_bf16(ah1, bl, acc[1][n], 0, 0, 0);
        }
        __syncthreads();
    }
    // --- epilogue: bias + relu + store (D: col=lane&15, row=(lane>>4)*4+reg) ---
#pragma unroll
    for (int m = 0; m < 2; ++m) {
        int rbase = node0 + wv * 32 + m * 16 + lk * 4;
#pragma unroll
        for (int n = 0; n < 8; ++n) {
            int colb = n * 16 + lrow;
            float bb = bias[colb];
#pragma unroll
            for (int r = 0; r < 4; ++r) {
                int row = rbase + r;
                if (row < n_rows) {
                    float v = acc[m][n][r] + bb;
                    if (do_relu) v = fmaxf(v, 0.f);
                    out[(size_t)row * HID + colb] = v;
                }
            }
        }
    }
}

// ---------------- fused tail: layer-3 (2 rows/graph, fp32 VALU) + product head ----------------
__global__ __launch_bounds__(256) void k_tail(const float* __restrict__ x2c,
                                              const int* __restrict__ sel,
                                              const int* __restrict__ remap,
                                              const int* __restrict__ start,
                                              const int* __restrict__ deg,
                                              const int* __restrict__ csr_src,
                                              const float* __restrict__ Wl3,
                                              const float* __restrict__ Wr3,
                                              const float* __restrict__ b3,
                                              const float* __restrict__ w1,
                                              const float* __restrict__ b1,
                                              const float* __restrict__ w2,
                                              const float* __restrict__ b2,
                                              float* __restrict__ out, int n_graphs) {
    int g = blockIdx.x;
    if (g >= n_graphs) return;
    __shared__ float sagg[2][HID];
    __shared__ float sxs[2][HID];
    __shared__ float stmp[2][HID];
    __shared__ float sy[2][HID];
    __shared__ float sh[HID];
    __shared__ float sh2[HID];
    int t = threadIdx.x;
    int wv = t >> 6, lane = t & 63;
    int r = wv >> 1;       // node slot 0/1
    int par = wv & 1;      // edge parity within slot
    int node = sel[2 * g + r];
    int s = start[node], dgr = deg[node], e = s + dgr;
    float2 acc = {0.f, 0.f};
    for (int i = s + par; i < e; i += 2) {
        int sr = remap[csr_src[i]];
        float2 v = ((const float2*)x2c)[(size_t)sr * 64 + lane];
        acc.x += v.x; acc.y += v.y;
    }
    if (par == 1) { stmp[r][2 * lane] = acc.x; stmp[r][2 * lane + 1] = acc.y; }
    __syncthreads();
    if (par == 0) {
        float di = 1.0f / fmaxf((float)dgr, 1.0f);
        sagg[r][2 * lane]     = (acc.x + stmp[r][2 * lane]) * di;
        sagg[r][2 * lane + 1] = (acc.y + stmp[r][2 * lane + 1]) * di;
        int xr = remap[node];
        float2 xv = ((const float2*)x2c)[(size_t)xr * 64 + lane];
        sxs[r][2 * lane] = xv.x; sxs[r][2 * lane + 1] = xv.y;
    }
    __syncthreads();
    // y[r][d] = dot(sagg[r], Wl3[d]) + dot(sxs[r], Wr3[d]) + b3[d]
    {
        int r2 = t >> 7;
        int d = t & 127;
        const float4* wl = (const float4*)(Wl3 + (size_t)d * HID);
        const float4* wr = (const float4*)(Wr3 + (size_t)d * HID);
        float a = 0.f;
#pragma unroll 8
        for (int k4 = 0; k4 < HID / 4; ++k4) {
            float4 w = wl[k4];
            float4 v = *(const float4*)&sagg[r2][k4 * 4];
            a += w.x * v.x + w.y * v.y + w.z * v.z + w.w * v.w;
            float4 w2v = wr[k4];
            float4 x = *(const float4*)&sxs[r2][k4 * 4];
            a += w2v.x * x.x + w2v.y * x.y + w2v.z * x.z + w2v.w * x.w;
        }
        sy[r2][d] = a + b3[d];
    }
    __syncthreads();
    if (t < HID) sh[t] = sy[0][t] * sy[1][t];
    __syncthreads();
    if (t < HID) {
        const float4* wr1 = (const float4*)(w1 + (size_t)t * HID);
        float a = b1[t];
#pragma unroll 8
        for (int k4 = 0; k4 < HID / 4; ++k4) {
            float4 w = wr1[k4];
            float4 h = *(const float4*)&sh[k4 * 4];
            a += w.x * h.x + w.y * h.y + w.z * h.z + w.w * h.w;
        }
        sh2[t] = fmaxf(a, 0.f) * w2[t];
    }
    __syncthreads();
    if (wv == 0) {
        float p = sh2[lane] + sh2[lane + 64];
#pragma unroll
        for (int off = 32; off > 0; off >>= 1) p += __shfl_down(p, off);
        if (lane == 0) out[g] = p + b2[0];
    }
}

extern "C" void kernel_launch(void* const* d_in, const int* in_sizes, int n_in,
                              void* d_out, int out_size, void* d_ws, size_t ws_size,
                              hipStream_t stream) {
    const int* z = (const int*)d_in[0];
    const int* edge_index = (const int*)d_in[1];
    const int* batch = (const int*)d_in[2];
    const float* z_emb = (const float*)d_in[4];
    const float* Wl = (const float*)d_in[5];
    const float* bl = (const float*)d_in[6];
    const float* Wr = (const float*)d_in[7];
    const float* lin1_w = (const float*)d_in[8];
    const float* lin1_b = (const float*)d_in[9];
    const float* lin2_w = (const float*)d_in[10];
    const float* lin2_b = (const float*)d_in[11];
    float* out = (float*)d_out;

    int n_nodes = in_sizes[0];
    int n_edges = in_sizes[1] / 2;
    int max_z = in_sizes[4] / HID;   // z_emb rows
    int n_graphs = out_size;         // output is [n_graphs, 1]

    const int* e_src = edge_index;
    const int* e_dst = edge_index + n_edges;

    char* p = (char*)d_ws;
    auto alloc = [&](size_t bytes) {
        char* r = p;
        p += (bytes + 511) & ~(size_t)511;
        return r;
    };
    float* x       = (float*)alloc((size_t)n_nodes * HID * 4);   // x1 (full)
    float* agg2    = (float*)alloc((size_t)n_nodes * HID * 4);   // layer-2 agg, compact
    float* x2c     = (float*)alloc((size_t)n_nodes * HID * 4);   // x2, compact
    int*   deg     = (int*)alloc((size_t)n_nodes * 4);
    int*   start   = (int*)alloc((size_t)n_nodes * 4);
    int2*  ebuf    = (int2*)alloc((size_t)n_edges * 8);
    int*   csr_src = (int*)alloc((size_t)n_edges * 4);
    int*   csr_zoff= (int*)alloc((size_t)n_edges * 4);
    int B = (n_edges + CHUNK - 1) / CHUNK;
    int*   hist     = (int*)alloc((size_t)B * NBIN * 4);
    int*   bintotal = (int*)alloc((size_t)NBIN * 4);
    int*   binbase  = (int*)alloc((size_t)(NBIN + 1) * 4);
    int*   sel    = (int*)alloc((size_t)(2 * n_graphs) * 4);
    int*   flag   = (int*)alloc((size_t)n_nodes * 4);
    int*   remap  = (int*)alloc((size_t)n_nodes * 4);
    int*   nodes2 = (int*)alloc((size_t)n_nodes * 4);
    int*   n2     = (int*)alloc(4);
    float* zl     = (float*)alloc((size_t)max_z * HID * 4);
    float* zr     = (float*)alloc((size_t)max_z * HID * 4);
    unsigned short* wh  = (unsigned short*)alloc((size_t)3 * HID * 2 * HID * 2);
    unsigned short* wlo = (unsigned short*)alloc((size_t)3 * HID * 2 * HID * 2);

    int wsplit_blocks = (3 * HID * 2 * HID + 255) / 256;
    k_prep<<<max_z + wsplit_blocks, 256, 0, stream>>>(z_emb, Wl, Wr, bl, zl, zr,
                                                      wh, wlo, max_z);

    // ---- atomic-free CSR build: 2-level counting sort (5 dispatches, fence-free) ----
    k_hist<<<B, 256, 0, stream>>>(e_dst, hist, n_edges);
    k_colscan<<<NBIN, 256, 0, stream>>>(hist, bintotal, B);
    k_binbase<<<1, 256, 0, stream>>>(bintotal, binbase);
    k_route<<<B, 256, 0, stream>>>(e_src, e_dst, hist, binbase, ebuf, n_edges);
    k_group<<<NBIN, 256, 0, stream>>>(ebuf, binbase, z, csr_src, csr_zoff,
                                      start, deg, flag, n2, n_nodes);

    // reachability for layer-2: sel ∪ srcs(sel edges), then compact
    k_centerflag<<<n_graphs, 64, 0, stream>>>(batch, start, deg, csr_src, sel, flag,
                                              n_nodes, n_graphs);
    k_flagcount<<<(n_nodes + 255) / 256, 256, 0, stream>>>(flag, remap, nodes2, n2, n_nodes);

    int agg_blocks = (n_nodes + 3) / 4;
    // layer 1 (full, fused): x1 = relu(deginv * sum(zl[z_src]) + zr[z[node]])
    k_agg<1><<<agg_blocks, 256, 0, stream>>>(zl, x, start, deg, csr_src, csr_zoff,
                                             nullptr, z, zr, n_nodes, nullptr);
    // layer 2 (compact over nodes2): persistent-stride waves, device row count
    k_agg<2><<<2048, 256, 0, stream>>>(x, agg2, start, deg, csr_src, nullptr, nodes2,
                                       nullptr, nullptr, 0, n2);
    k_gemm<<<(n_nodes + GM - 1) / GM, 256, 0, stream>>>(agg2, x, x2c,
                                            wh + (size_t)HID * 2 * HID,
                                            wlo + (size_t)HID * 2 * HID,
                                            bl + HID, nodes2, 0, n2, 1);
    // layer 3 + head, fused (fp32)
    k_tail<<<n_graphs, 256, 0, stream>>>(x2c, sel, remap, start, deg, csr_src,
                                         Wl + (size_t)2 * HID * HID,
                                         Wr + (size_t)2 * HID * HID,
                                         bl + (size_t)2 * HID,
                                         lin1_w, lin1_b, lin2_w, lin2_b,
                                         out, n_graphs);
}

// Round 14
// 258.574 us; speedup vs baseline: 1.1270x; 1.0645x over previous
//
#include <hip/hip_runtime.h>
#include <hip/hip_bf16.h>
#include <cstdint>

#define HID 128
#define GM 128          // rows per GEMM block
#define NBIN 512        // low-9-bit buckets
#define CHUNK 2048      // edges per histogram/route block
#define MAXHI 1024      // max (n_nodes/NBIN) supported

typedef __attribute__((ext_vector_type(8))) short bf16x8;
typedef __attribute__((ext_vector_type(4))) float f32x4;

__device__ __forceinline__ unsigned short f2bf(float f) {
    union { __hip_bfloat16 h; unsigned short u; } c;
    c.h = __float2bfloat16(f);
    return c.u;
}
__device__ __forceinline__ float bf2f(unsigned short u) {
    union { unsigned int i; float f; } c;
    c.i = ((unsigned int)u) << 16;
    return c.f;
}
__device__ __forceinline__ unsigned int pack2(unsigned short a, unsigned short b) {
    return (unsigned int)a | ((unsigned int)b << 16);
}
__device__ __forceinline__ bf16x8 ld_frag(const unsigned int* p) {
    union { uint4 u; bf16x8 f; } c;
    c.u = *(const uint4*)p;
    return c.f;
}

// exclusive block scan over 256 threads (wave shfl + LDS wave totals).
__device__ __forceinline__ int block_scan_excl(int v, int t, int* wtot, int* tot) {
    int lane = t & 63, wv = t >> 6;
    int incl = v;
#pragma unroll
    for (int off = 1; off < 64; off <<= 1) {
        int u = __shfl_up(incl, off);
        if (lane >= off) incl += u;
    }
    if (lane == 63) wtot[wv] = incl;
    __syncthreads();
    int woff = 0;
    for (int w = 0; w < wv; ++w) woff += wtot[w];
    if (tot) *tot = wtot[0] + wtot[1] + wtot[2] + wtot[3];
    __syncthreads();   // allow wtot reuse
    return woff + incl - v;
}

// ---------------- fused prep: zl/zr tables (blocks < max_z) + W split (rest) ----------------
__global__ void k_prep(const float* __restrict__ z_emb, const float* __restrict__ Wl,
                       const float* __restrict__ Wr, const float* __restrict__ bl,
                       float* __restrict__ zl, float* __restrict__ zr,
                       unsigned short* __restrict__ wh, unsigned short* __restrict__ wlo,
                       int max_z) {
    int t = threadIdx.x;
    if ((int)blockIdx.x < max_z) {
        __shared__ float row[HID];
        int r = blockIdx.x;
        if (t < HID) row[t] = z_emb[(size_t)r * HID + t];
        __syncthreads();
        int d = t & 127;
        const float* w = (t < 128 ? Wl : Wr) + (size_t)d * HID;
        float acc = 0.f;
#pragma unroll
        for (int k4 = 0; k4 < HID / 4; ++k4) {
            float4 wv = *(const float4*)(w + k4 * 4);
            float4 hv = *(const float4*)&row[k4 * 4];
            acc += wv.x * hv.x + wv.y * hv.y + wv.z * hv.z + wv.w * hv.w;
        }
        if (t < 128) zl[(size_t)r * HID + d] = acc;
        else         zr[(size_t)r * HID + d] = acc + bl[d];
    } else {
        int idx = (blockIdx.x - max_z) * 256 + t;
        if (idx >= 3 * HID * 2 * HID) return;
        int l = idx / (HID * 2 * HID);
        int r = idx - l * (HID * 2 * HID);
        int d = r >> 8;
        int k = r & 255;
        float v = (k < HID) ? Wl[((size_t)l * HID + d) * HID + k]
                            : Wr[((size_t)l * HID + d) * HID + (k - HID)];
        unsigned short h = f2bf(v);
        unsigned short lo = f2bf(v - bf2f(h));
        wh[idx] = h;
        wlo[idx] = lo;
    }
}

// ---------------- pass 1a: per-block 512-bin histogram of dst low bits ----------------
__global__ __launch_bounds__(256) void k_hist(const int* __restrict__ dst,
                                              int* __restrict__ hist, int n_edges) {
    __shared__ int h[NBIN];
    int t = threadIdx.x;
    h[t] = 0; h[t + 256] = 0;
    __syncthreads();
    int base = blockIdx.x * CHUNK;
#pragma unroll
    for (int j = 0; j < CHUNK / 256; ++j) {
        int e = base + j * 256 + t;
        if (e < n_edges) atomicAdd(&h[dst[e] & (NBIN - 1)], 1);
    }
    __syncthreads();
    hist[(size_t)blockIdx.x * NBIN + t] = h[t];
    hist[(size_t)blockIdx.x * NBIN + t + 256] = h[t + 256];
}

// ---------------- pass 1b: per-bin exclusive scan over blocks (in place; plain stores) ----
__global__ __launch_bounds__(256) void k_colscan(int* __restrict__ hist,
                                                 int* __restrict__ bintotal, int B) {
    __shared__ int wtot[4];
    int k = blockIdx.x, t = threadIdx.x;
    int run = 0;
    for (int base = 0; base < B; base += 256) {
        int b = base + t;
        int v = (b < B) ? hist[(size_t)b * NBIN + k] : 0;
        int tot;
        int excl = block_scan_excl(v, t, wtot, &tot);
        if (b < B) hist[(size_t)b * NBIN + k] = run + excl;
        run += tot;
    }
    if (t == 0) bintotal[k] = run;
}

// ---------------- pass 1c: exclusive scan of 512 bin totals ----------------
__global__ __launch_bounds__(256) void k_binbase(const int* __restrict__ bintotal,
                                                 int* __restrict__ binbase) {
    __shared__ int wtot[4];
    int t = threadIdx.x;
    int a0 = bintotal[2 * t], a1 = bintotal[2 * t + 1];
    int excl = block_scan_excl(a0 + a1, t, wtot, nullptr);
    binbase[2 * t] = excl;
    binbase[2 * t + 1] = excl + a0;
    if (t == 255) binbase[NBIN] = excl + a0 + a1;
}

// ---------------- pass 1d: route edges into bin regions (LDS ranks, no global atomics) --
__global__ __launch_bounds__(256) void k_route(const int* __restrict__ src,
                                               const int* __restrict__ dst,
                                               const int* __restrict__ histex,
                                               const int* __restrict__ binbase,
                                               int2* __restrict__ ebuf, int n_edges) {
    __shared__ int h2[NBIN];
    __shared__ int basel[NBIN];
    int t = threadIdx.x;
    h2[t] = 0; h2[t + 256] = 0;
    basel[t]       = binbase[t]       + histex[(size_t)blockIdx.x * NBIN + t];
    basel[t + 256] = binbase[t + 256] + histex[(size_t)blockIdx.x * NBIN + t + 256];
    __syncthreads();
    int base = blockIdx.x * CHUNK;
#pragma unroll
    for (int j = 0; j < CHUNK / 256; ++j) {
        int e = base + j * 256 + t;
        if (e < n_edges) {
            int d = dst[e], s = src[e];
            int bin = d & (NBIN - 1);
            int r = atomicAdd(&h2[bin], 1);
            ebuf[basel[bin] + r] = make_int2(s, d);
        }
    }
}

// ---------------- pass 2: exact grouping by node; also zeroes flag[] and n2 ----------------
__global__ __launch_bounds__(256) void k_group(const int2* __restrict__ ebuf,
                                               const int* __restrict__ binbase,
                                               const int* __restrict__ z,
                                               int* __restrict__ csr_src,
                                               int* __restrict__ csr_zoff,
                                               int* __restrict__ start, int* __restrict__ deg,
                                               int* __restrict__ flag, int* __restrict__ n2,
                                               int n_nodes) {
    __shared__ int hh[MAXHI];
    __shared__ int cur[MAXHI];
    __shared__ int wtot[4];
    int k = blockIdx.x, t = threadIdx.x;
    if (k == 0 && t == 0) n2[0] = 0;
    int rs = binbase[k], re = binbase[k + 1];
#pragma unroll
    for (int j = 0; j < MAXHI / 256; ++j) hh[t + j * 256] = 0;
    __syncthreads();
    for (int i = rs + t; i < re; i += 256)
        atomicAdd(&hh[ebuf[i].y >> 9], 1);
    __syncthreads();
    int idx = t * 4;
    int a0 = hh[idx], a1 = hh[idx + 1], a2 = hh[idx + 2], a3 = hh[idx + 3];
    int excl = block_scan_excl(a0 + a1 + a2 + a3, t, wtot, nullptr);
    int e0 = excl, e1 = e0 + a0, e2 = e1 + a1, e3 = e2 + a2;
    cur[idx] = e0; cur[idx + 1] = e1; cur[idx + 2] = e2; cur[idx + 3] = e3;
    int ee[4] = {e0, e1, e2, e3};
    int aa[4] = {a0, a1, a2, a3};
#pragma unroll
    for (int j = 0; j < 4; ++j) {
        int node = ((idx + j) << 9) | k;
        if (node < n_nodes) {
            start[node] = rs + ee[j];
            deg[node] = aa[j];
            flag[node] = 0;
        }
    }
    __syncthreads();
    for (int i = rs + t; i < re; i += 256) {
        int2 sd = ebuf[i];
        int r = rs + atomicAdd(&cur[sd.y >> 9], 1);
        csr_src[r] = sd.x;
        csr_zoff[r] = z[sd.x] << 9;
    }
}

// ---------------- center search + flag sel nodes and their edge sources ----------------
__global__ void k_centerflag(const int* __restrict__ batch, const int* __restrict__ start,
                             const int* __restrict__ deg, const int* __restrict__ csr_src,
                             int* __restrict__ sel, int* __restrict__ flag,
                             int n_nodes, int n_graphs) {
    int g = blockIdx.x;
    if (g >= n_graphs) return;
    int lane = threadIdx.x;   // 64
    int lo = 0, hi = n_nodes;
    while (lo < hi) {
        int mid = (lo + hi) >> 1;
        if (batch[mid] < g) lo = mid + 1;
        else hi = mid;
    }
    int s0 = min(lo, n_nodes - 1);       // JAX index clamp semantics
    int s1 = min(lo + 1, n_nodes - 1);
    if (lane == 0) { sel[2 * g] = s0; sel[2 * g + 1] = s1; flag[s0] = 1; flag[s1] = 1; }
    int a = start[s0], e = a + deg[s0];
    for (int i = a + lane; i < e; i += 64) flag[csr_src[i]] = 1;
    a = start[s1]; e = a + deg[s1];
    for (int i = a + lane; i < e; i += 64) flag[csr_src[i]] = 1;
}

// ---------------- flag -> remap + compact list; ONE device atomic per block ----------------
// nodes2 order is nondeterministic across calls, but output is invariant to it.
__global__ __launch_bounds__(256) void k_flagcount(const int* __restrict__ flag,
                            int* __restrict__ remap,
                            int* __restrict__ nodes2, int* __restrict__ n2, int n) {
    __shared__ int wtot[4];
    __shared__ int sbase;
    int t = threadIdx.x;
    int i = blockIdx.x * 256 + t;
    int f = (i < n) ? flag[i] : 0;
    int tot;
    int excl = block_scan_excl(f, t, wtot, &tot);
    if (t == 0) sbase = atomicAdd(n2, tot);
    __syncthreads();
    int pos = sbase + excl;
    if (i < n) {
        remap[i] = pos;
        if (f) nodes2[pos] = i;
    }
}

// ---------------- mean aggregation: persistent waves, one wave per row ----------------
// MODE 1 (layer-1 fused): node=r, gather zl via csr_zoff; epilogue +zr[z[node]] & relu -> x1.
// MODE 2 (layer-2 compact): node=idxmap[r]=nodes2[r], gather x via csr_src, out compact.
template<int MODE>
__global__ __launch_bounds__(256) void k_agg(const float* __restrict__ xv_,
                      float* __restrict__ aggout,
                      const int* __restrict__ start, const int* __restrict__ deg,
                      const int* __restrict__ csr_src, const int* __restrict__ csr_zoff,
                      const int* __restrict__ idxmap,
                      const int* __restrict__ z, const float* __restrict__ zr,
                      int n_host, const int* __restrict__ n_dev) {
    int nw_total = gridDim.x * 4;
    int w0 = blockIdx.x * 4 + (threadIdx.x >> 6);
    int lane = threadIdx.x & 63;
    int n = n_dev ? *n_dev : n_host;
    int half = lane >> 5;
    int col = lane & 31;
    const float4* xv = (const float4*)xv_;
    const char* xc = (const char*)xv_;
    for (int r = w0; r < n; r += nw_total) {
        int node = (MODE == 1) ? r : idxmap[r];
        int s = start[node];
        int dg = deg[node];
        int e = s + dg;
        float4 a0 = {0.f,0.f,0.f,0.f}, a1 = {0.f,0.f,0.f,0.f};
        float4 a2 = {0.f,0.f,0.f,0.f}, a3 = {0.f,0.f,0.f,0.f};
        int i = s + half;
        if (MODE == 1) {
            for (; i + 6 < e; i += 8) {   // 4 rows in flight per half-wave
                int o0 = csr_zoff[i];
                int o1 = csr_zoff[i + 2];
                int o2 = csr_zoff[i + 4];
                int o3 = csr_zoff[i + 6];
                float4 v0 = *(const float4*)(xc + o0 + col * 16);
                float4 v1 = *(const float4*)(xc + o1 + col * 16);
                float4 v2 = *(const float4*)(xc + o2 + col * 16);
                float4 v3 = *(const float4*)(xc + o3 + col * 16);
                a0.x += v0.x; a0.y += v0.y; a0.z += v0.z; a0.w += v0.w;
                a1.x += v1.x; a1.y += v1.y; a1.z += v1.z; a1.w += v1.w;
                a2.x += v2.x; a2.y += v2.y; a2.z += v2.z; a2.w += v2.w;
                a3.x += v3.x; a3.y += v3.y; a3.z += v3.z; a3.w += v3.w;
            }
            for (; i < e; i += 2) {
                float4 v0 = *(const float4*)(xc + csr_zoff[i] + col * 16);
                a0.x += v0.x; a0.y += v0.y; a0.z += v0.z; a0.w += v0.w;
            }
        } else {
            for (; i + 6 < e; i += 8) {
                int s0 = csr_src[i];
                int s1 = csr_src[i + 2];
                int s2 = csr_src[i + 4];
                int s3 = csr_src[i + 6];
                float4 v0 = xv[(size_t)s0 * 32 + col];
                float4 v1 = xv[(size_t)s1 * 32 + col];
                float4 v2 = xv[(size_t)s2 * 32 + col];
                float4 v3 = xv[(size_t)s3 * 32 + col];
                a0.x += v0.x; a0.y += v0.y; a0.z += v0.z; a0.w += v0.w;
                a1.x += v1.x; a1.y += v1.y; a1.z += v1.z; a1.w += v1.w;
                a2.x += v2.x; a2.y += v2.y; a2.z += v2.z; a2.w += v2.w;
                a3.x += v3.x; a3.y += v3.y; a3.z += v3.z; a3.w += v3.w;
            }
            for (; i < e; i += 2) {
                float4 v0 = xv[(size_t)csr_src[i] * 32 + col];
                a0.x += v0.x; a0.y += v0.y; a0.z += v0.z; a0.w += v0.w;
            }
        }
        a0.x += a1.x + a2.x + a3.x;
        a0.y += a1.y + a2.y + a3.y;
        a0.z += a1.z + a2.z + a3.z;
        a0.w += a1.w + a2.w + a3.w;
        a0.x += __shfl_xor(a0.x, 32);
        a0.y += __shfl_xor(a0.y, 32);
        a0.z += __shfl_xor(a0.z, 32);
        a0.w += __shfl_xor(a0.w, 32);
        if (half == 0) {
            float di = 1.0f / fmaxf((float)dg, 1.0f);
            float4 o = make_float4(a0.x * di, a0.y * di, a0.z * di, a0.w * di);
            if (MODE == 1) {
                int zn = z[node];
                float4 rv = ((const float4*)zr)[(size_t)zn * 32 + col];
                o.x = fmaxf(o.x + rv.x, 0.f);
                o.y = fmaxf(o.y + rv.y, 0.f);
                o.z = fmaxf(o.z + rv.z, 0.f);
                o.w = fmaxf(o.w + rv.w, 0.f);
            }
            ((float4*)aggout)[(size_t)r * 32 + col] = o;
        }
    }
}

// ---------------- fused layer GEMM via split-bf16 MFMA (layer 2) ----------------
__global__ __launch_bounds__(256) void k_gemm(const float* __restrict__ aggsrc,
                                              const float* __restrict__ xsrc,
                                              float* __restrict__ out,
                                              const unsigned short* __restrict__ wh,
                                              const unsigned short* __restrict__ wlo,
                                              const float* __restrict__ bias,
                                              const int* __restrict__ xidx,
                                              int n_host, const int* __restrict__ n_dev,
                                              int do_relu) {
    __shared__ unsigned int sAh[GM * 16], sAl[GM * 16];
    __shared__ unsigned int sBh[HID * 16], sBl[HID * 16];
    int n_rows = n_dev ? *n_dev : n_host;
    int t = threadIdx.x;
    int node0 = blockIdx.x * GM;
    if (node0 >= n_rows) return;
    int wv = t >> 6, lane = t & 63;
    int lrow = lane & 15, lk = lane >> 4;

    f32x4 acc[2][8];
#pragma unroll
    for (int m = 0; m < 2; ++m)
#pragma unroll
        for (int n = 0; n < 8; ++n) acc[m][n] = (f32x4){0.f, 0.f, 0.f, 0.f};

    int srow = t >> 2;      // 0..63 (+64 for rr=1)
    int sq = t & 3;         // quarter of the 32-k row

    int gg[2] = {node0 + srow, node0 + srow + 64};
    bool vv[2] = {gg[0] < n_rows, gg[1] < n_rows};
    int xr[2];
#pragma unroll
    for (int rr = 0; rr < 2; ++rr)
        xr[rr] = xidx ? (vv[rr] ? xidx[gg[rr]] : 0) : gg[rr];

    for (int c = 0; c < 8; ++c) {
        int kbase = (c & 3) * 32;
        int kb = c * 32;
        // --- stage A: 128 rows x 32 k, fp32 -> split bf16 hi/lo ---
#pragma unroll
        for (int rr = 0; rr < 2; ++rr) {
            int row = srow + rr * 64;
            const float* srcrow = (c < 4) ? aggsrc + (size_t)gg[rr] * HID
                                          : xsrc + (size_t)xr[rr] * HID;
            float f[8];
            if (vv[rr]) {
                const float4* rp = (const float4*)(srcrow + kbase + sq * 8);
                float4 v0 = rp[0], v1 = rp[1];
                f[0]=v0.x; f[1]=v0.y; f[2]=v0.z; f[3]=v0.w;
                f[4]=v1.x; f[5]=v1.y; f[6]=v1.z; f[7]=v1.w;
            } else {
#pragma unroll
                for (int j = 0; j < 8; ++j) f[j] = 0.f;
            }
            unsigned int h[4], l[4];
#pragma unroll
            for (int j = 0; j < 4; ++j) {
                unsigned short h0 = f2bf(f[2*j]), h1 = f2bf(f[2*j+1]);
                unsigned short l0 = f2bf(f[2*j] - bf2f(h0));
                unsigned short l1 = f2bf(f[2*j+1] - bf2f(h1));
                h[j] = pack2(h0, h1);
                l[j] = pack2(l0, l1);
            }
            unsigned int base = row * 16 + sq * 4;
            *(uint4*)&sAh[base] = make_uint4(h[0], h[1], h[2], h[3]);
            *(uint4*)&sAl[base] = make_uint4(l[0], l[1], l[2], l[3]);
        }
        // --- stage B: 128 d-rows x 32 k, bf16 copy ---
#pragma unroll
        for (int rr = 0; rr < 2; ++rr) {
            int d = srow + rr * 64;
            size_t go = (size_t)d * 256 + kb + sq * 8;
            uint4 vh = *(const uint4*)(wh + go);
            uint4 vl = *(const uint4*)(wlo + go);
            unsigned int base = d * 16 + sq * 4;
            *(uint4*)&sBh[base] = vh;
            *(uint4*)&sBl[base] = vl;
        }
        __syncthreads();
        // --- compute: 2 M-tiles x 8 N-tiles x 3 split products ---
        bf16x8 ah0, al0, ah1, al1;
        {
            unsigned int a0 = (unsigned)(wv * 32 + lrow) * 16 + lk * 4;
            unsigned int a1 = (unsigned)(wv * 32 + 16 + lrow) * 16 + lk * 4;
            ah0 = ld_frag(&sAh[a0]); al0 = ld_frag(&sAl[a0]);
            ah1 = ld_frag(&sAh[a1]); al1 = ld_frag(&sAl[a1]);
        }
#pragma unroll
        for (int n = 0; n < 8; ++n) {
            unsigned int b = (unsigned)(n * 16 + lrow) * 16 + lk * 4;
            bf16x8 bh = ld_frag(&sBh[b]);
            bf16x8 bl = ld_frag(&sBl[b]);
            acc[0][n] = __builtin_amdgcn_mfma_f32_16x16x32_bf16(ah0, bh, acc[0][n], 0, 0, 0);
            acc[0][n] = __builtin_amdgcn_mfma_f32_16x16x32_bf16(al0, bh, acc[0][n], 0, 0, 0);
            acc[0][n] = __builtin_amdgcn_mfma_f32_16x16x32_bf16(ah0, bl, acc[0][n], 0, 0, 0);
            acc[1][n] = __builtin_amdgcn_mfma_f32_16x16x32_bf16(ah1, bh, acc[1][n], 0, 0, 0);
            acc[1][n] = __builtin_amdgcn_mfma_f32_16x16x32_bf16(al1, bh, acc[1][n], 0, 0, 0);
            acc[1][n] = __builtin_amdgcn_mfma_f32_16x16x32_bf16(ah1, bl, acc[1][n], 0, 0, 0);
        }
        __syncthreads();
    }
    // --- epilogue: bias + relu + store (D: col=lane&15, row=(lane>>4)*4+reg) ---
#pragma unroll
    for (int m = 0; m < 2; ++m) {
        int rbase = node0 + wv * 32 + m * 16 + lk * 4;
#pragma unroll
        for (int n = 0; n < 8; ++n) {
            int colb = n * 16 + lrow;
            float bb = bias[colb];
#pragma unroll
            for (int r = 0; r < 4; ++r) {
                int row = rbase + r;
                if (row < n_rows) {
                    float v = acc[m][n][r] + bb;
                    if (do_relu) v = fmaxf(v, 0.f);
                    out[(size_t)row * HID + colb] = v;
                }
            }
        }
    }
}

// ---------------- fused tail: layer-3 (2 rows/graph, fp32 VALU) + product head ----------------
// Gather restructured to MODE-3 style: float4/lane, half-wave edge split, stride-4 across
// the slot's 2 waves, 2-deep unroll -> 8 rows in flight per node slot.
__global__ __launch_bounds__(256) void k_tail(const float* __restrict__ x2c,
                                              const int* __restrict__ sel,
                                              const int* __restrict__ remap,
                                              const int* __restrict__ start,
                                              const int* __restrict__ deg,
                                              const int* __restrict__ csr_src,
                                              const float* __restrict__ Wl3,
                                              const float* __restrict__ Wr3,
                                              const float* __restrict__ b3,
                                              const float* __restrict__ w1,
                                              const float* __restrict__ b1,
                                              const float* __restrict__ w2,
                                              const float* __restrict__ b2,
                                              float* __restrict__ out, int n_graphs) {
    int g = blockIdx.x;
    if (g >= n_graphs) return;
    __shared__ float stmp[2][2][HID];
    __shared__ float sagg[2][HID];
    __shared__ float sxs[2][HID];
    __shared__ float sy[2][HID];
    __shared__ float sh[HID];
    __shared__ float sh2[HID];
    int t = threadIdx.x;
    int wv = t >> 6, lane = t & 63;
    int r = wv >> 1;       // node slot 0/1
    int par = wv & 1;      // wave parity within slot
    int half = lane >> 5;  // half-wave
    int col = lane & 31;   // float4 column
    int node = sel[2 * g + r];
    int s = start[node], dgr = deg[node], e = s + dgr;
    float4 a0 = {0.f,0.f,0.f,0.f}, a1 = {0.f,0.f,0.f,0.f};
    int i = s + 2 * par + half;   // offsets {0,1,2,3} mod 4 across slot's 2 waves
    for (; i + 4 < e; i += 8) {   // 2 rows in flight per half-wave
        int r0 = remap[csr_src[i]];
        int r1 = remap[csr_src[i + 4]];
        float4 v0 = ((const float4*)x2c)[(size_t)r0 * 32 + col];
        float4 v1 = ((const float4*)x2c)[(size_t)r1 * 32 + col];
        a0.x += v0.x; a0.y += v0.y; a0.z += v0.z; a0.w += v0.w;
        a1.x += v1.x; a1.y += v1.y; a1.z += v1.z; a1.w += v1.w;
    }
    for (; i < e; i += 4) {
        int r0 = remap[csr_src[i]];
        float4 v0 = ((const float4*)x2c)[(size_t)r0 * 32 + col];
        a0.x += v0.x; a0.y += v0.y; a0.z += v0.z; a0.w += v0.w;
    }
    a0.x += a1.x; a0.y += a1.y; a0.z += a1.z; a0.w += a1.w;
    a0.x += __shfl_xor(a0.x, 32);
    a0.y += __shfl_xor(a0.y, 32);
    a0.z += __shfl_xor(a0.z, 32);
    a0.w += __shfl_xor(a0.w, 32);
    if (half == 0) {
        ((float4*)stmp[r][par])[col] = a0;
        if (par == 1) {   // self row, concurrently
            int xr = remap[node];
            ((float4*)sxs[r])[col] = ((const float4*)x2c)[(size_t)xr * 32 + col];
        }
    }
    __syncthreads();
    if (par == 0 && half == 0) {
        float di = 1.0f / fmaxf((float)dgr, 1.0f);
        float4 u = ((float4*)stmp[r][0])[col];
        float4 w = ((float4*)stmp[r][1])[col];
        ((float4*)sagg[r])[col] = make_float4((u.x + w.x) * di, (u.y + w.y) * di,
                                              (u.z + w.z) * di, (u.w + w.w) * di);
    }
    __syncthreads();
    // y[r][d] = dot(sagg[r], Wl3[d]) + dot(sxs[r], Wr3[d]) + b3[d]
    {
        int r2 = t >> 7;
        int d = t & 127;
        const float4* wl = (const float4*)(Wl3 + (size_t)d * HID);
        const float4* wr = (const float4*)(Wr3 + (size_t)d * HID);
        float a = 0.f;
#pragma unroll 8
        for (int k4 = 0; k4 < HID / 4; ++k4) {
            float4 w = wl[k4];
            float4 v = *(const float4*)&sagg[r2][k4 * 4];
            a += w.x * v.x + w.y * v.y + w.z * v.z + w.w * v.w;
            float4 w2v = wr[k4];
            float4 x = *(const float4*)&sxs[r2][k4 * 4];
            a += w2v.x * x.x + w2v.y * x.y + w2v.z * x.z + w2v.w * x.w;
        }
        sy[r2][d] = a + b3[d];
    }
    __syncthreads();
    if (t < HID) sh[t] = sy[0][t] * sy[1][t];
    __syncthreads();
    if (t < HID) {
        const float4* wr1 = (const float4*)(w1 + (size_t)t * HID);
        float a = b1[t];
#pragma unroll 8
        for (int k4 = 0; k4 < HID / 4; ++k4) {
            float4 w = wr1[k4];
            float4 h = *(const float4*)&sh[k4 * 4];
            a += w.x * h.x + w.y * h.y + w.z * h.z + w.w * h.w;
        }
        sh2[t] = fmaxf(a, 0.f) * w2[t];
    }
    __syncthreads();
    if (wv == 0) {
        float p = sh2[lane] + sh2[lane + 64];
#pragma unroll
        for (int off = 32; off > 0; off >>= 1) p += __shfl_down(p, off);
        if (lane == 0) out[g] = p + b2[0];
    }
}

extern "C" void kernel_launch(void* const* d_in, const int* in_sizes, int n_in,
                              void* d_out, int out_size, void* d_ws, size_t ws_size,
                              hipStream_t stream) {
    const int* z = (const int*)d_in[0];
    const int* edge_index = (const int*)d_in[1];
    const int* batch = (const int*)d_in[2];
    const float* z_emb = (const float*)d_in[4];
    const float* Wl = (const float*)d_in[5];
    const float* bl = (const float*)d_in[6];
    const float* Wr = (const float*)d_in[7];
    const float* lin1_w = (const float*)d_in[8];
    const float* lin1_b = (const float*)d_in[9];
    const float* lin2_w = (const float*)d_in[10];
    const float* lin2_b = (const float*)d_in[11];
    float* out = (float*)d_out;

    int n_nodes = in_sizes[0];
    int n_edges = in_sizes[1] / 2;
    int max_z = in_sizes[4] / HID;   // z_emb rows
    int n_graphs = out_size;         // output is [n_graphs, 1]

    const int* e_src = edge_index;
    const int* e_dst = edge_index + n_edges;

    char* p = (char*)d_ws;
    auto alloc = [&](size_t bytes) {
        char* r = p;
        p += (bytes + 511) & ~(size_t)511;
        return r;
    };
    float* x       = (float*)alloc((size_t)n_nodes * HID * 4);   // x1 (full)
    float* agg2    = (float*)alloc((size_t)n_nodes * HID * 4);   // layer-2 agg, compact
    float* x2c     = (float*)alloc((size_t)n_nodes * HID * 4);   // x2, compact
    int*   deg     = (int*)alloc((size_t)n_nodes * 4);
    int*   start   = (int*)alloc((size_t)n_nodes * 4);
    int2*  ebuf    = (int2*)alloc((size_t)n_edges * 8);
    int*   csr_src = (int*)alloc((size_t)n_edges * 4);
    int*   csr_zoff= (int*)alloc((size_t)n_edges * 4);
    int B = (n_edges + CHUNK - 1) / CHUNK;
    int*   hist     = (int*)alloc((size_t)B * NBIN * 4);
    int*   bintotal = (int*)alloc((size_t)NBIN * 4);
    int*   binbase  = (int*)alloc((size_t)(NBIN + 1) * 4);
    int*   sel    = (int*)alloc((size_t)(2 * n_graphs) * 4);
    int*   flag   = (int*)alloc((size_t)n_nodes * 4);
    int*   remap  = (int*)alloc((size_t)n_nodes * 4);
    int*   nodes2 = (int*)alloc((size_t)n_nodes * 4);
    int*   n2     = (int*)alloc(4);
    float* zl     = (float*)alloc((size_t)max_z * HID * 4);
    float* zr     = (float*)alloc((size_t)max_z * HID * 4);
    unsigned short* wh  = (unsigned short*)alloc((size_t)3 * HID * 2 * HID * 2);
    unsigned short* wlo = (unsigned short*)alloc((size_t)3 * HID * 2 * HID * 2);

    int wsplit_blocks = (3 * HID * 2 * HID + 255) / 256;
    k_prep<<<max_z + wsplit_blocks, 256, 0, stream>>>(z_emb, Wl, Wr, bl, zl, zr,
                                                      wh, wlo, max_z);

    // ---- atomic-free CSR build: 2-level counting sort (5 dispatches, fence-free) ----
    k_hist<<<B, 256, 0, stream>>>(e_dst, hist, n_edges);
    k_colscan<<<NBIN, 256, 0, stream>>>(hist, bintotal, B);
    k_binbase<<<1, 256, 0, stream>>>(bintotal, binbase);
    k_route<<<B, 256, 0, stream>>>(e_src, e_dst, hist, binbase, ebuf, n_edges);
    k_group<<<NBIN, 256, 0, stream>>>(ebuf, binbase, z, csr_src, csr_zoff,
                                      start, deg, flag, n2, n_nodes);

    // reachability for layer-2: sel ∪ srcs(sel edges), then compact
    k_centerflag<<<n_graphs, 64, 0, stream>>>(batch, start, deg, csr_src, sel, flag,
                                              n_nodes, n_graphs);
    k_flagcount<<<(n_nodes + 255) / 256, 256, 0, stream>>>(flag, remap, nodes2, n2, n_nodes);

    int agg_blocks = (n_nodes + 3) / 4;
    // layer 1 (full, fused): x1 = relu(deginv * sum(zl[z_src]) + zr[z[node]])
    k_agg<1><<<agg_blocks, 256, 0, stream>>>(zl, x, start, deg, csr_src, csr_zoff,
                                             nullptr, z, zr, n_nodes, nullptr);
    // layer 2 (compact over nodes2): persistent-stride waves, device row count
    k_agg<2><<<2048, 256, 0, stream>>>(x, agg2, start, deg, csr_src, nullptr, nodes2,
                                       nullptr, nullptr, 0, n2);
    k_gemm<<<(n_nodes + GM - 1) / GM, 256, 0, stream>>>(agg2, x, x2c,
                                            wh + (size_t)HID * 2 * HID,
                                            wlo + (size_t)HID * 2 * HID,
                                            bl + HID, nodes2, 0, n2, 1);
    // layer 3 + head, fused (fp32)
    k_tail<<<n_graphs, 256, 0, stream>>>(x2c, sel, remap, start, deg, csr_src,
                                         Wl + (size_t)2 * HID * HID,
                                         Wr + (size_t)2 * HID * HID,
                                         bl + (size_t)2 * HID,
                                         lin1_w, lin1_b, lin2_w, lin2_b,
                                         out, n_graphs);
}